// Round 3
// baseline (192.959 us; speedup 1.0000x reference)
//
#include <hip/hip_runtime.h>

#define DEVINL __device__ __forceinline__

// 3-level a-trous B3-spline UWT, barrier-free per-wave row streaming.
// Wave = one 256-col strip (float4/lane, halo 16 each side, 224 valid) x one
// 32-row band. Horizontal convs via wave-wide DPP shifts; vertical convs via
// register delay lines (x, h0, c1, c2) and per-wave LDS rings (h1 span 9,
// h2 span 17). No __syncthreads anywhere.

constexpr int W = 1024, H = 1024;
constexpr int VALID = 224, HALO = 16;
constexpr int NSX = 5;                 // 4*224 + 128 = 1024
constexpr int ROUT = 32;
constexpr int NBY = H / ROUT;          // 32

constexpr float TPa = 1.0f / 16.0f;
constexpr float TPb = 1.0f / 4.0f;
constexpr float TPc = 3.0f / 8.0f;

// HW-verified (round 2): ctrl 0x11N = value from lane i-N (row), 0x10N = lane
// i+N. Wave-wide variants: 0x138 wave_shr1 = lane i-1, 0x130 wave_shl1 =
// lane i+1. bound_ctrl=1 -> 0 shifted in at wave edges (halo lanes only).
template <int CTRL>
DEVINL float dppf(float x) {
    return __int_as_float(__builtin_amdgcn_update_dpp(
        0, __float_as_int(x), CTRL, 0xF, 0xF, true));
}
constexpr int WSHR = 0x138;  // from lane i-1
constexpr int WSHL = 0x130;  // from lane i+1

DEVINL float4 shrf4(float4 v) {
    float4 r;
    r.x = dppf<WSHR>(v.x); r.y = dppf<WSHR>(v.y);
    r.z = dppf<WSHR>(v.z); r.w = dppf<WSHR>(v.w);
    return r;
}
DEVINL float4 shlf4(float4 v) {
    float4 r;
    r.x = dppf<WSHL>(v.x); r.y = dppf<WSHL>(v.y);
    r.z = dppf<WSHL>(v.z); r.w = dppf<WSHL>(v.w);
    return r;
}

DEVINL float4 conv5(float4 a, float4 b, float4 c, float4 d, float4 e) {
    float4 r;
    r.x = TPa * (a.x + e.x) + TPb * (b.x + d.x) + TPc * c.x;
    r.y = TPa * (a.y + e.y) + TPb * (b.y + d.y) + TPc * c.y;
    r.z = TPa * (a.z + e.z) + TPb * (b.z + d.z) + TPc * c.z;
    r.w = TPa * (a.w + e.w) + TPb * (b.w + d.w) + TPc * c.w;
    return r;
}
DEVINL float4 f4sub(float4 a, float4 b) {
    float4 r;
    r.x = a.x - b.x; r.y = a.y - b.y; r.z = a.z - b.z; r.w = a.w - b.w;
    return r;
}

// horizontal 5-tap, dilation 1 (cols +/-1, +/-2); lane owns cols 4L..4L+3
DEVINL float4 hconv1(float4 v) {
    const float am1 = dppf<WSHR>(v.w), am2 = dppf<WSHR>(v.z);
    const float ap1 = dppf<WSHL>(v.x), ap2 = dppf<WSHL>(v.y);
    float4 u;
    u.x = TPa * (am2 + v.z) + TPb * (am1 + v.y) + TPc * v.x;
    u.y = TPa * (am1 + v.w) + TPb * (v.x + v.z) + TPc * v.y;
    u.z = TPa * (v.x + ap1) + TPb * (v.y + v.w) + TPc * v.z;
    u.w = TPa * (v.y + ap2) + TPb * (v.z + ap1) + TPc * v.w;
    return u;
}
// dilation 2 (cols +/-2, +/-4)
DEVINL float4 hconv2(float4 v) {
    const float4 am = shrf4(v), ap = shlf4(v);
    float4 u;
    u.x = TPa * (am.x + ap.x) + TPb * (am.z + v.z) + TPc * v.x;
    u.y = TPa * (am.y + ap.y) + TPb * (am.w + v.w) + TPc * v.y;
    u.z = TPa * (am.z + ap.z) + TPb * (v.x + ap.x) + TPc * v.z;
    u.w = TPa * (am.w + ap.w) + TPb * (v.y + ap.y) + TPc * v.w;
    return u;
}
// dilation 4 (cols +/-4 = lane -/+1, +/-8 = lane -/+2)
DEVINL float4 hconv4(float4 v) {
    const float4 am = shrf4(v), ap = shlf4(v);
    const float4 bm = shrf4(am), bp = shlf4(ap);
    float4 u;
    u.x = TPa * (bm.x + bp.x) + TPb * (am.x + ap.x) + TPc * v.x;
    u.y = TPa * (bm.y + bp.y) + TPb * (am.y + ap.y) + TPc * v.y;
    u.z = TPa * (bm.z + bp.z) + TPb * (am.z + ap.z) + TPc * v.z;
    u.w = TPa * (bm.w + bp.w) + TPb * (am.w + ap.w) + TPc * v.w;
    return u;
}

DEVINL int reflx(int g) {
    g = g < 0 ? -g : g;
    return g >= W ? 2 * W - 2 - g : g;
}

DEVINL float4 loadrow(const float* __restrict__ xb, int r, int col,
                      int o0, int o1, int o2, int o3, bool edge) {
    r = r < 0 ? -r : r;
    if (r >= H) r = 2 * H - 2 - r;
    const float* row = xb + (size_t)r * W;
    if (!edge) return *(const float4*)(row + col);
    float4 v;
    v.x = row[o0]; v.y = row[o1]; v.z = row[o2]; v.w = row[o3];
    return v;
}

DEVINL int wrap9(int v)  { return v >= 9  ? v - 9  : v; }
DEVINL int wrap17(int v) { return v >= 17 ? v - 17 : v; }

// Pipeline at step t (t = t0+u, t0 = y0-14, t0 mod 8 == 2):
//   consume x[t] -> h0[t] -> c1[t-2] -> h1[t-2] -> c2[t-6] -> h2[t-6]
//   -> c3[t-14]; outputs: w1@t-2, w2@t-6, w3/c3@t-14; prefetch x[t+2].
#define STEP(U8)                                                              \
    do {                                                                      \
        constexpr int P = (U8 + 2) & 7; /* t mod 8 */                         \
        const int u = it * 8 + (U8);                                          \
        const int tt = t0 + u;                                                \
        const float4 xv = xin[P];                                             \
        const float4 h0 = hconv1(xv);                                         \
        h0r[P] = h0;                                                          \
        const float4 c1 = conv5(h0r[(P + 4) & 7], h0r[(P + 5) & 7],           \
                                h0r[(P + 6) & 7], h0r[(P + 7) & 7], h0);      \
        if (u >= 16 && u < 48 && lok)                                         \
            *(float4*)(ow1 + (size_t)(tt - 2) * W) =                          \
                f4sub(xin[(P + 6) & 7], c1);                                  \
        const float4 h1 = hconv2(c1);                                         \
        const int s1 = wrap9(i9 + 1), s3 = wrap9(i9 + 3);                     \
        const int s5 = wrap9(i9 + 5), s7 = wrap9(i9 + 7);                     \
        const float4 c2 =                                                     \
            conv5(h1ring[s1 * 64 + lane], h1ring[s3 * 64 + lane],             \
                  h1ring[s5 * 64 + lane], h1ring[s7 * 64 + lane], h1);        \
        h1ring[i9 * 64 + lane] = h1;                                          \
        constexpr int C1S = (P + 2) & 3; /* (t-2)&3 == (t-6)&3 */             \
        if (u >= 20 && u < 52 && lok)                                         \
            *(float4*)(ow2 + (size_t)(tt - 6) * W) = f4sub(c1d[C1S], c2);     \
        c1d[C1S] = c1;                                                        \
        const float4 h2 = hconv4(c2);                                         \
        const int r1 = wrap17(i17 + 1), r5 = wrap17(i17 + 5);                 \
        const int r9 = wrap17(i17 + 9), r13 = wrap17(i17 + 13);               \
        const float4 c3 =                                                     \
            conv5(h2ring[r1 * 64 + lane], h2ring[r5 * 64 + lane],             \
                  h2ring[r9 * 64 + lane], h2ring[r13 * 64 + lane], h2);       \
        h2ring[i17 * 64 + lane] = h2;                                         \
        constexpr int C2S = (P + 2) & 7; /* (t-6)&7 == (t-14)&7 */            \
        if (u >= 28 && u < 60 && lok) {                                       \
            *(float4*)(ow3 + (size_t)(tt - 14) * W) = f4sub(c2d[C2S], c3);    \
            *(float4*)(oc3 + (size_t)(tt - 14) * W) = c3;                     \
        }                                                                     \
        c2d[C2S] = c2;                                                        \
        if (u < 60)                                                           \
            xin[(P + 2) & 7] =                                                \
                loadrow(xb, tt + 2, col, o0, o1, o2, o3, edge);               \
        i9 = wrap9(i9 + 1);                                                   \
        i17 = wrap17(i17 + 1);                                                \
    } while (0)

__global__ __launch_bounds__(64, 2)
void uwt_stream(const float* __restrict__ x, float* __restrict__ out) {
    __shared__ float4 h1ring[9 * 64];   //  9216 B
    __shared__ float4 h2ring[17 * 64];  // 17408 B -> 26624 total, 6 waves/CU

    int bid = blockIdx.x;
    const int sx = bid % NSX;  bid /= NSX;
    const int by = bid % NBY;
    const int b  = bid / NBY;
    const int lane = threadIdx.x;
    const int y0 = by * ROUT;
    const int t0 = y0 - 14;                       // t0 mod 8 == 2 always
    const int col = sx * VALID - HALO + lane * 4;
    const bool edge = (sx == 0) || (sx == NSX - 1);
    const int o0 = reflx(col),     o1 = reflx(col + 1);
    const int o2 = reflx(col + 2), o3 = reflx(col + 3);
    const bool lok = (lane >= 4) && (lane < 60) && (col < W);
    const float* xb = x + (size_t)b * (H * W);
    float* ow1 = out + (size_t)(b * 4 + 0) * (H * W) + col;
    float* ow2 = out + (size_t)(b * 4 + 1) * (H * W) + col;
    float* ow3 = out + (size_t)(b * 4 + 2) * (H * W) + col;
    float* oc3 = out + (size_t)(b * 4 + 3) * (H * W) + col;

    float4 xin[8], h0r[8], c1d[4], c2d[8];
    // prime the x pipe: x[t0] -> slot t0&7 == 2, x[t0+1] -> 3
    xin[2] = loadrow(xb, t0, col, o0, o1, o2, o3, edge);
    xin[3] = loadrow(xb, t0 + 1, col, o0, o1, o2, o3, edge);
    int i9 = 0, i17 = 0;

#pragma unroll 1
    for (int it = 0; it < 8; ++it) {
        STEP(0); STEP(1); STEP(2); STEP(3);
        STEP(4); STEP(5); STEP(6); STEP(7);
    }
}

extern "C" void kernel_launch(void* const* d_in, const int* in_sizes, int n_in,
                              void* d_out, int out_size, void* d_ws,
                              size_t ws_size, hipStream_t stream) {
    const float* x = (const float*)d_in[0];
    float* out = (float*)d_out;
    const int nb = in_sizes[0] / (H * W);          // 8
    dim3 grid(nb * NBY * NSX);                     // 8*32*5 = 1280
    uwt_stream<<<grid, 64, 0, stream>>>(x, out);
}